// Round 1
// baseline (877.583 us; speedup 1.0000x reference)
//
#include <hip/hip_runtime.h>

#define N_NODES 200000
#define N_EDGES 400000
#define N_GRAPHS 64
#define HDIM 128
#define INDIM 5
#define LN_EPS 1e-5f
#define LDA 140  // 70 dwords/row: 70 mod 32 = 6 -> frag reads distributed; t1-write q-groups hit disjoint bank octets
#define NPBLK 64 // nodes per block (4 waves x 16 rows) -- R12 verified config

typedef __attribute__((ext_vector_type(8))) short short8;
typedef __attribute__((ext_vector_type(4))) float f32x4;
typedef __attribute__((ext_vector_type(2))) float f32x2;

__device__ __forceinline__ unsigned short to_bf(float v) {
    unsigned u = __builtin_bit_cast(unsigned, v);
    return (unsigned short)((u + 0x7FFFu + ((u >> 16) & 1u)) >> 16);
}
__device__ __forceinline__ float bf_lo(unsigned w) { return __builtin_bit_cast(float, w << 16); }
__device__ __forceinline__ float bf_hi(unsigned w) { return __builtin_bit_cast(float, w & 0xFFFF0000u); }
__device__ __forceinline__ float bf2f(unsigned short h) { return __builtin_bit_cast(float, (unsigned)h << 16); }

// 1-instr RTNE f32->bf16 (same rounding as to_bf); single-value form uses low half
__device__ __forceinline__ unsigned short cvt1_bf(float v) {
    unsigned r;
    asm("v_cvt_pk_bf16_f32 %0, %1, %1" : "=v"(r) : "v"(v));
    return (unsigned short)r;
}
__device__ __forceinline__ unsigned cvt2_bf(float lo, float hi) {
    unsigned r;
    asm("v_cvt_pk_bf16_f32 %0, %1, %2" : "=v"(r) : "v"(lo), "v"(hi));
    return r;
}
__device__ __forceinline__ f32x2 vmax0(f32x2 v) {
#if __has_builtin(__builtin_elementwise_max)
    return __builtin_elementwise_max(v, (f32x2)0.f);
#else
    v.x = fmaxf(v.x, 0.f);
    v.y = fmaxf(v.y, 0.f);
    return v;
#endif
}

// message accumulate for one edge: acc += relu((x + eb) + a*ew), 16 channel-pairs (packed f32x2)
__device__ __forceinline__ void gproc(uint4 w0, uint4 w1, uint4 w2, uint4 w3, float a_,
                                      const float4* ep, f32x2* accv) {
    unsigned ws[16] = {w0.x, w0.y, w0.z, w0.w, w1.x, w1.y, w1.z, w1.w,
                       w2.x, w2.y, w2.z, w2.w, w3.x, w3.y, w3.z, w3.w};
    f32x2 av = a_;
#pragma unroll
    for (int p = 0; p < 16; ++p) {
        float4 wb = ep[p];  // {ew0, ew1, eb0, eb1} -- broadcast ds_read_b128, conflict-free
        f32x2 xv;
        xv.x = bf_lo(ws[p]);
        xv.y = bf_hi(ws[p]);
        f32x2 ew2, eb2;
        ew2.x = wb.x;
        ew2.y = wb.y;
        eb2.x = wb.z;
        eb2.y = wb.w;
        f32x2 t = xv + eb2;
        t = av * ew2 + t;
        accv[p] += vmax0(t);
    }
}

// ---------------- CSR build ----------------

__global__ void hist_kernel(const int* __restrict__ ei, int* __restrict__ deg) {
    int e = blockIdx.x * blockDim.x + threadIdx.x;
    if (e < N_EDGES) atomicAdd(&deg[ei[N_EDGES + e]], 1);
}

#define SCAN_CHUNK 1024
#define SCAN_BLOCKS ((N_NODES + SCAN_CHUNK - 1) / SCAN_CHUNK)  // 196

// also zeroes pool+cnt (block 0) -- saves a memset range
__global__ __launch_bounds__(256) void scan_phaseA(const int* __restrict__ deg, int* __restrict__ bsums,
                                                   int* __restrict__ poolz) {
    if (blockIdx.x == 0) {
        for (int i = threadIdx.x; i < N_GRAPHS * HDIM + N_GRAPHS; i += 256) poolz[i] = 0;
    }
    __shared__ int red[256];
    int t = threadIdx.x;
    int base = blockIdx.x * SCAN_CHUNK + t * 4;
    int s = 0;
#pragma unroll
    for (int k = 0; k < 4; ++k) {
        int i = base + k;
        s += (i < N_NODES) ? deg[i] : 0;
    }
    red[t] = s;
    __syncthreads();
    for (int off = 128; off; off >>= 1) {
        if (t < off) red[t] += red[t + off];
        __syncthreads();
    }
    if (t == 0) bsums[blockIdx.x] = red[0];
}

__global__ __launch_bounds__(256) void scan_phaseB(int* __restrict__ bsums, int* __restrict__ row_ptr) {
    __shared__ int s[256];
    int t = threadIdx.x;
    int v = (t < SCAN_BLOCKS) ? bsums[t] : 0;
    s[t] = v;
    __syncthreads();
    for (int off = 1; off < 256; off <<= 1) {
        int add = (t >= off) ? s[t - off] : 0;
        __syncthreads();
        s[t] += add;
        __syncthreads();
    }
    if (t < SCAN_BLOCKS) bsums[t] = s[t] - v;  // exclusive
    if (t == SCAN_BLOCKS - 1) row_ptr[N_NODES] = s[t];
}

// also zeroes cursor -- saves a memset range
__global__ __launch_bounds__(256) void scan_phaseC(const int* __restrict__ deg,
                                                   const int* __restrict__ bsums,
                                                   int* __restrict__ row_ptr,
                                                   int* __restrict__ cursor) {
    __shared__ int ts[256];
    int t = threadIdx.x;
    int base = blockIdx.x * SCAN_CHUNK + t * 4;
    int v[4];
    int s = 0;
#pragma unroll
    for (int k = 0; k < 4; ++k) {
        int i = base + k;
        v[k] = (i < N_NODES) ? deg[i] : 0;
        s += v[k];
    }
    ts[t] = s;
    __syncthreads();
    for (int off = 1; off < 256; off <<= 1) {
        int add = (t >= off) ? ts[t - off] : 0;
        __syncthreads();
        ts[t] += add;
        __syncthreads();
    }
    int run = bsums[blockIdx.x] + ts[t] - s;
#pragma unroll
    for (int k = 0; k < 4; ++k) {
        int i = base + k;
        if (i < N_NODES) { row_ptr[i] = run; cursor[i] = 0; }
        run += v[k];
    }
}

// ---------------- Fused scatter (CSR fill) + weight packing ----------------
#define SCATTER_BLOCKS ((N_EDGES + 255) / 256)  // 1563

__global__ void scatter_pack(const int* __restrict__ ei, const float* __restrict__ ea,
                             const int* __restrict__ row_ptr, int* __restrict__ cursor,
                             int2* __restrict__ csr,
                             const float* __restrict__ s0, short* __restrict__ d0,
                             const float* __restrict__ s1, short* __restrict__ d1,
                             const float* __restrict__ s2, short* __restrict__ d2,
                             const float* __restrict__ s3, short* __restrict__ d3,
                             const float* __restrict__ s4, short* __restrict__ d4,
                             const float* __restrict__ s5, short* __restrict__ d5) {
    int b = blockIdx.x;
    if (b < SCATTER_BLOCKS) {
        int e = b * 256 + threadIdx.x;
        if (e >= N_EDGES) return;
        int d = ei[N_EDGES + e];
        int pos = atomicAdd(&cursor[d], 1);
        csr[row_ptr[d] + pos] = make_int2(ei[e], __float_as_int(ea[e]));
        return;
    }
    b -= SCATTER_BLOCKS;
    const float* W;
    short* D;
    int din, KP, b0;
    if (b < 16)       { W = s0; D = d0; din = 5;   KP = 32;  b0 = 0; }
    else if (b < 80)  { W = s1; D = d1; din = 128; KP = 128; b0 = 16; }
    else if (b < 144) { W = s2; D = d2; din = 128; KP = 128; b0 = 80; }
    else if (b < 208) { W = s3; D = d3; din = 128; KP = 128; b0 = 144; }
    else if (b < 272) { W = s4; D = d4; din = 128; KP = 128; b0 = 208; }
    else              { W = s5; D = d5; din = 128; KP = 128; b0 = 272; }
    int idx = (b - b0) * 256 + threadIdx.x;
    if (idx >= KP * 128) return;
    int j = idx & 7;
    int lane = (idx >> 3) & 63;
    int rest = idx >> 9;
    int KS = KP >> 5;
    int kstep = rest % KS;
    int tile = rest / KS;
    int k = kstep * 32 + ((lane >> 4) * 8) + j;
    int n = tile * 16 + (lane & 15);
    float v = (k < din) ? W[k * 128 + n] : 0.f;
    D[idx] = (short)to_bf(v);
}

// ---------------- Fused layer: gather + MFMA MLP + reg-LN + ReLU (+pool) ----------------
// 256 threads = 4 waves; 64 nodes/block. (256,4): VGPR cap 128, no spill
// (any min-waves >4 under-allocates and spills: R9/R11/R13 evidence).
template <int KP1, bool POOL>
__global__ __launch_bounds__(256, 4) void layer_fused(
    const void* __restrict__ xin_v, const int* __restrict__ row_ptr,
    const int2* __restrict__ csr,
    const float* __restrict__ ew, const float* __restrict__ eb,
    const short* __restrict__ w1h, const float* __restrict__ b1,
    const short* __restrict__ w2h, const float* __restrict__ b2,
    const float* __restrict__ g, const float* __restrict__ bt,
    unsigned short* __restrict__ xout,
    const int* __restrict__ batch, float* __restrict__ pool, int* __restrict__ cnt) {
    __shared__ __align__(16) unsigned short A16[NPBLK * LDA];
    __shared__ int bidx[NPBLK];
    union Scratch {
        float eweb4[4 * 17 * 4];                       // padded {ew,ew,eb,eb} float4 table (din=128 path)
        float part[KP1 == 128 ? 1 : NPBLK][4][INDIM];  // layer-0 gather partials
    };
    __shared__ __align__(16) Scratch u;

    int tid = threadIdx.x;
    int node0 = blockIdx.x * NPBLK;

    if constexpr (KP1 == 128) {
        const unsigned short* xin = (const unsigned short*)xin_v;
        // stage padded edge-encoder table: group qt at float4 stride 17 (bank-conflict-free broadcast reads)
        if (tid < 64) {
            int qq = tid >> 4, ii = tid & 15, c = qq * 32 + ii * 2;
            ((float4*)u.eweb4)[qq * 17 + ii] = make_float4(ew[c], ew[c + 1], eb[c], eb[c + 1]);
        }
        if (POOL && tid >= 64 && tid < 128) bidx[tid - 64] = batch[node0 + tid - 64];

        // thread = (row, 32-channel quarter); packed f32x2 accumulators in registers
        int row = tid >> 2, qt = tid & 3, c0 = qt * 32;
        int node = node0 + row;

        // issue own-row loads early
        const uint4* xn = (const uint4*)(xin + (size_t)node * 128 + c0);
        uint4 own0 = xn[0], own1 = xn[1], own2 = xn[2], own3 = xn[3];
        int beg = row_ptr[node], end = row_ptr[node + 1];

        // 2-edge pipeline preamble: prefetch csr records + x-rows for edges beg, beg+1
        int2 rA, rB;
        uint4 a0, a1, a2, a3, b0, b1v4, b2v4, b3;
        if (beg < end) {
            rA = csr[beg];
            const uint4* xs = (const uint4*)(xin + (size_t)rA.x * 128 + c0);
            a0 = xs[0]; a1 = xs[1]; a2 = xs[2]; a3 = xs[3];
        }
        if (beg + 1 < end) {
            rB = csr[beg + 1];
            const uint4* xs = (const uint4*)(xin + (size_t)rB.x * 128 + c0);
            b0 = xs[0]; b1v4 = xs[1]; b2v4 = xs[2]; b3 = xs[3];
        }
        __syncthreads();  // eweb4 ready (loads above are in flight across the barrier wait)
        const float4* ep = ((const float4*)u.eweb4) + qt * 17;

        f32x2 accv[16];
        {
            unsigned ws[16] = {own0.x, own0.y, own0.z, own0.w, own1.x, own1.y, own1.z, own1.w,
                               own2.x, own2.y, own2.z, own2.w, own3.x, own3.y, own3.z, own3.w};
#pragma unroll
            for (int p = 0; p < 16; ++p) {
                accv[p].x = bf_lo(ws[p]);
                accv[p].y = bf_hi(ws[p]);
            }
        }

        // software-pipelined gather: while edge e is consumed, edge e+2's row is loading
        int e = beg;
        while (e + 1 < end) {
            int2 rN = rA, rM = rB;
            bool hasN = (e + 2 < end), hasM = (e + 3 < end);
            if (hasN) rN = csr[e + 2];
            if (hasM) rM = csr[e + 3];
            gproc(a0, a1, a2, a3, __int_as_float(rA.y), ep, accv);
            if (hasN) {
                const uint4* xs = (const uint4*)(xin + (size_t)rN.x * 128 + c0);
                a0 = xs[0]; a1 = xs[1]; a2 = xs[2]; a3 = xs[3];
            }
            gproc(b0, b1v4, b2v4, b3, __int_as_float(rB.y), ep, accv);
            if (hasM) {
                const uint4* xs = (const uint4*)(xin + (size_t)rM.x * 128 + c0);
                b0 = xs[0]; b1v4 = xs[1]; b2v4 = xs[2]; b3 = xs[3];
            }
            rA = rN;
            rB = rM;
            e += 2;
        }
        if (e < end) gproc(a0, a1, a2, a3, __int_as_float(rA.y), ep, accv);

        // packed cvt + uint2 stores (2-way bank aliasing only = free)
        uint2* Ar2 = (uint2*)&A16[row * LDA + c0];
#pragma unroll
        for (int k = 0; k < 8; ++k) {
            Ar2[k] = make_uint2(cvt2_bf(accv[2 * k].x, accv[2 * k].y),
                                cvt2_bf(accv[2 * k + 1].x, accv[2 * k + 1].y));
        }
        // no barrier: rows [16wv,16wv+16) are written and read by the same wave
    } else {
        // layer 0 (din=5): 4 threads/row split the edge list; register partials
        const float* xinf = (const float*)xin_v;
        int row = tid >> 2, qt = tid & 3;
        int node = node0 + row;
        {
            float w[INDIM], b[INDIM], acc[INDIM];
#pragma unroll
            for (int j = 0; j < INDIM; ++j) {
                w[j] = ew[j];
                b[j] = eb[j];
                acc[j] = 0.f;
            }
            int beg = row_ptr[node], end = row_ptr[node + 1];
            int2 r;
            if (beg + qt < end) r = csr[beg + qt];
            for (int e = beg + qt; e < end; e += 4) {
                int2 rn = (e + 4 < end) ? csr[e + 4] : r;
                float a = __int_as_float(r.y);
#pragma unroll
                for (int j = 0; j < INDIM; ++j)
                    acc[j] += fmaxf(fmaf(a, w[j], xinf[r.x * INDIM + j] + b[j]), 0.f);
                r = rn;
            }
#pragma unroll
            for (int j = 0; j < INDIM; ++j) u.part[row][qt][j] = acc[j];
        }
        __syncthreads();
        if (tid < NPBLK) {
#pragma unroll
            for (int j = 0; j < INDIM; ++j) {
                float v = xinf[(node0 + tid) * INDIM + j] + u.part[tid][0][j] + u.part[tid][1][j] +
                          u.part[tid][2][j] + u.part[tid][3][j];
                A16[tid * LDA + j] = cvt1_bf(v);
            }
#pragma unroll
            for (int j = INDIM; j < 32; ++j) A16[tid * LDA + j] = 0;
        }
        __syncthreads();  // rows written by tid<64 -> cross-wave
    }

    // ---- MFMA MLP (wave-local rows) ----
    int wv = tid >> 6, lane = tid & 63;
    int mrow = lane & 15, q = lane >> 4;
    int arow = wv * 16 + mrow;

    const short8* w1p = (const short8*)w1h;
    const short8* w2p = (const short8*)w2h;

    f32x4 acc2[8];
#pragma unroll
    for (int t = 0; t < 8; ++t) acc2[t] = (f32x4){0.f, 0.f, 0.f, 0.f};
    constexpr int KS1 = KP1 / 32;
#pragma unroll
    for (int ks = 0; ks < KS1; ++ks) {
        short8 bh[8];
#pragma unroll
        for (int t = 0; t < 8; ++t) bh[t] = w1p[((size_t)t * KS1 + ks) * 64 + lane];
        short8 ah = *(const short8*)&A16[arow * LDA + ks * 32 + q * 8];
#pragma unroll
        for (int t = 0; t < 8; ++t)
            acc2[t] = __builtin_amdgcn_mfma_f32_16x16x32_bf16(ah, bh[t], acc2[t], 0, 0, 0);
    }
    // t1 = relu(acc + b1) -> bf16 A (wave-local rows)
    {
        float b1v[8];
#pragma unroll
        for (int t = 0; t < 8; ++t) b1v[t] = b1[t * 16 + mrow];
#pragma unroll
        for (int t = 0; t < 8; ++t)
#pragma unroll
            for (int r = 0; r < 4; ++r) {
                int rrow = wv * 16 + q * 4 + r;
                int col = t * 16 + mrow;
                A16[rrow * LDA + col] = cvt1_bf(fmaxf(acc2[t][r] + b1v[t], 0.f));
            }
    }

    // GEMM2 (K = 128); A reads wave-local
#pragma unroll
    for (int t = 0; t < 8; ++t) acc2[t] = (f32x4){0.f, 0.f, 0.f, 0.f};
#pragma unroll
    for (int ks = 0; ks < 4; ++ks) {
        short8 bh[8];
#pragma unroll
        for (int t = 0; t < 8; ++t) bh[t] = w2p[((size_t)t * 4 + ks) * 64 + lane];
        short8 ah = *(const short8*)&A16[arow * LDA + ks * 32 + q * 8];
#pragma unroll
        for (int t = 0; t < 8; ++t)
            acc2[t] = __builtin_amdgcn_mfma_f32_16x16x32_bf16(ah, bh[t], acc2[t], 0, 0, 0);
    }

    // ---- LayerNorm in registers (rows live in 16-lane groups) ----
    float s4[4] = {0.f, 0.f, 0.f, 0.f}, q4[4] = {0.f, 0.f, 0.f, 0.f};
    {
        float b2v[8];
#pragma unroll
        for (int t = 0; t < 8; ++t) b2v[t] = b2[t * 16 + mrow];
#pragma unroll
        for (int t = 0; t < 8; ++t)
#pragma unroll
            for (int r = 0; r < 4; ++r) {
                float v = acc2[t][r] + b2v[t];
                acc2[t][r] = v;
                s4[r] += v;
                q4[r] += v * v;
            }
    }
#pragma unroll
    for (int m = 1; m <= 8; m <<= 1) {
#pragma unroll
        for (int r = 0; r < 4; ++r) {
            s4[r] += __shfl_xor(s4[r], m, 64);
            q4[r] += __shfl_xor(q4[r], m, 64);
        }
    }
    float mu[4], inv[4];
#pragma unroll
    for (int r = 0; r < 4; ++r) {
        mu[r] = s4[r] * (1.f / HDIM);
        float var = q4[r] * (1.f / HDIM) - mu[r] * mu[r];
        inv[r] = rsqrtf(var + LN_EPS);
    }
    float gv[8], btv[8];
#pragma unroll
    for (int t = 0; t < 8; ++t) {
        gv[t] = g[t * 16 + mrow];
        btv[t] = bt[t * 16 + mrow];
    }

    // LN result -> LDS (wave-local row writes; no pre-barrier needed)
#pragma unroll
    for (int t = 0; t < 8; ++t)
#pragma unroll
        for (int r = 0; r < 4; ++r) {
            int rrow = wv * 16 + q * 4 + r;
            int col = t * 16 + mrow;
            float o = fmaxf((acc2[t][r] - mu[r]) * inv[r] * gv[t] + btv[t], 0.f);
            A16[rrow * LDA + col] = cvt1_bf(o);
        }
    __syncthreads();  // epilogue reads all rows (cross-wave)

    if (!POOL) {
        // coalesced copy-out: wave inst covers 256 contiguous bytes (4 full lines)
        unsigned* xo = (unsigned*)xout;
#pragma unroll
        for (int i = 0; i < 16; ++i) {
            int idx = tid + 256 * i;       // 4096 = 64 rows x 64 words
            int row = idx >> 6, w = idx & 63;
            xo[(size_t)(node0 + row) * 64 + w] = ((const unsigned*)&A16[row * LDA])[w];
        }
    } else {
        if (tid < 128) {
            int col = tid;
            float accp = 0.f;
            int cur = bidx[0];
            for (int r = 0; r < NPBLK; ++r) {
                int gi = bidx[r];
                if (gi != cur) {
                    unsafeAtomicAdd(&pool[cur * HDIM + col], accp);
                    accp = 0.f;
                    cur = gi;
                }
                accp += bf2f(A16[r * LDA + col]);
            }
            unsafeAtomicAdd(&pool[cur * HDIM + col], accp);
        } else if (tid == 255) {
            int cur = bidx[0], c = 0;
            for (int r = 0; r < NPBLK; ++r) {
                if (bidx[r] != cur) {
                    atomicAdd(&cnt[cur], c);
                    c = 0;
                    cur = bidx[r];
                }
                ++c;
            }
            atomicAdd(&cnt[cur], c);
        }
    }
}

__global__ void pool_final(const float* __restrict__ pool, const int* __restrict__ cnt,
                           float* __restrict__ out) {
    int g = blockIdx.x, j = threadIdx.x;
    float add = pool[g * HDIM + j];
    float c = (float)max(cnt[g], 1);
    out[g * (2 * HDIM) + j] = add / c;
    out[g * (2 * HDIM) + HDIM + j] = add;
}

extern "C" void kernel_launch(void* const* d_in, const int* in_sizes, int n_in,
                              void* d_out, int out_size, void* d_ws, size_t ws_size,
                              hipStream_t stream) {
    const float* x_in = (const float*)d_in[0];
    const int* ei = (const int*)d_in[1];
    const float* ea = (const float*)d_in[2];
    const int* batch = (const int*)d_in[3];
    const float* P[24];
    for (int i = 0; i < 24; ++i) P[i] = (const float*)d_in[4 + i];
    // per layer l (base 8l): 0=ew 1=eb 2=w1 3=b1 4=w2 5=b2 6=g 7=bt

    unsigned short* x_a = (unsigned short*)d_ws;                 // N*128 bf16
    unsigned short* x_b = x_a + (size_t)N_NODES * HDIM;          // N*128 bf16
    float* pool = (float*)(x_b + (size_t)N_NODES * HDIM);        // G*128 (zeroed in scanA)
    int* cnt = (int*)(pool + N_GRAPHS * HDIM);                   // G    (zeroed in scanA)
    int* deg = cnt + N_GRAPHS;                                   // N    (memset)
    int* cursor = deg + N_NODES;                                 // N    (zeroed in scanC)
    int* row_ptr = cursor + N_NODES;                             // N+1
    int* bsums = row_ptr + N_NODES + 1;                          // pad 256 (keeps int2 8B-aligned)
    int2* csr = (int2*)(bsums + 256);                            // E (packed {src, val})
    short* wp = (short*)(((uintptr_t)(csr + N_EDGES) + 15) & ~(uintptr_t)15);
    float* out = (float*)d_out;

    short *w1h[3], *w2h[3];
    for (int l = 0; l < 3; ++l) {
        w1h[l] = wp + (size_t)l * 32768;
        w2h[l] = w1h[l] + 16384;
    }

    // ---- memset: deg only (pool/cnt zeroed in scanA, cursor in scanC) ----
    hipMemsetAsync(deg, 0, N_NODES * sizeof(int), stream);

    // ---- CSR build ----
    hist_kernel<<<(N_EDGES + 255) / 256, 256, 0, stream>>>(ei, deg);
    scan_phaseA<<<SCAN_BLOCKS, 256, 0, stream>>>(deg, bsums, (int*)pool);
    scan_phaseB<<<1, 256, 0, stream>>>(bsums, row_ptr);
    scan_phaseC<<<SCAN_BLOCKS, 256, 0, stream>>>(deg, bsums, row_ptr, cursor);

    // ---- fused scatter + weight packing (1563 + 336 blocks) ----
    scatter_pack<<<SCATTER_BLOCKS + 336, 256, 0, stream>>>(
        ei, ea, row_ptr, cursor, csr,
        P[2], w1h[0], P[4], w2h[0],
        P[10], w1h[1], P[12], w2h[1],
        P[18], w1h[2], P[20], w2h[2]);

    // ---- fused layers ----
    layer_fused<32, false><<<N_NODES / NPBLK, 256, 0, stream>>>(
        x_in, row_ptr, csr, P[0], P[1],
        w1h[0], P[3], w2h[0], P[5], P[6], P[7], x_a, nullptr, nullptr, nullptr);
    layer_fused<128, false><<<N_NODES / NPBLK, 256, 0, stream>>>(
        x_a, row_ptr, csr, P[8], P[9],
        w1h[1], P[11], w2h[1], P[13], P[14], P[15], x_b, nullptr, nullptr, nullptr);
    layer_fused<128, true><<<N_NODES / NPBLK, 256, 0, stream>>>(
        x_b, row_ptr, csr, P[16], P[17],
        w1h[2], P[19], w2h[2], P[21], P[22], P[23], nullptr, batch, pool, cnt);

    pool_final<<<N_GRAPHS, HDIM, 0, stream>>>(pool, cnt, out);
}

// Round 3
// 591.504 us; speedup vs baseline: 1.4836x; 1.4836x over previous
//
#include <hip/hip_runtime.h>

#define N_NODES 200000
#define N_EDGES 400000
#define N_GRAPHS 64
#define HDIM 128
#define INDIM 5
#define LN_EPS 1e-5f
#define LDA 140  // 70 dwords/row: 70 mod 32 = 6 -> frag reads distributed
#define NPBLK 64 // nodes per block (4 waves x 16 rows) -- R12 verified config

typedef __attribute__((ext_vector_type(8))) short short8;
typedef __attribute__((ext_vector_type(4))) float f32x4;
typedef __attribute__((ext_vector_type(2))) float f32x2;

__device__ __forceinline__ unsigned short to_bf(float v) {
    unsigned u = __builtin_bit_cast(unsigned, v);
    return (unsigned short)((u + 0x7FFFu + ((u >> 16) & 1u)) >> 16);
}
__device__ __forceinline__ float bf_lo(unsigned w) { return __builtin_bit_cast(float, w << 16); }
__device__ __forceinline__ float bf_hi(unsigned w) { return __builtin_bit_cast(float, w & 0xFFFF0000u); }
__device__ __forceinline__ float bf2f(unsigned short h) { return __builtin_bit_cast(float, (unsigned)h << 16); }

// 1-instr RTNE f32->bf16 (same rounding as to_bf); single-value form uses low half
__device__ __forceinline__ unsigned short cvt1_bf(float v) {
    unsigned r;
    asm("v_cvt_pk_bf16_f32 %0, %1, %1" : "=v"(r) : "v"(v));
    return (unsigned short)r;
}
__device__ __forceinline__ unsigned cvt2_bf(float lo, float hi) {
    unsigned r;
    asm("v_cvt_pk_bf16_f32 %0, %1, %2" : "=v"(r) : "v"(lo), "v"(hi));
    return r;
}

// ---- gather pipeline macros: explicit register names (no token pasting -- R2 lesson),
// no pointers to locals (R1 spill lesson), all indices compile-time.
#define GLOAD(q0, q1, q2, q3, srcrow)                                       \
    {                                                                       \
        const uint4* xs_ = (const uint4*)(xin + (size_t)(srcrow)*128 + c0); \
        q0 = xs_[0]; q1 = xs_[1]; q2 = xs_[2]; q3 = xs_[3];                 \
    }

// accv[p] += relu(x + eb + a*ew) for the 16 channel-pairs of buffer {q0..q3}
#define GPROC(q0, q1, q2, q3, a_)                                             \
    {                                                                         \
        unsigned ws_[16] = {q0.x, q0.y, q0.z, q0.w, q1.x, q1.y, q1.z, q1.w,   \
                            q2.x, q2.y, q2.z, q2.w, q3.x, q3.y, q3.z, q3.w};  \
        float av_ = (a_);                                                     \
        _Pragma("unroll") for (int p_ = 0; p_ < 16; ++p_) {                   \
            float4 wb_ = ep[p_]; /* {ew0,ew1,eb0,eb1} broadcast b128 */       \
            float tx_ = fmaxf(fmaf(av_, wb_.x, bf_lo(ws_[p_]) + wb_.z), 0.f); \
            float ty_ = fmaxf(fmaf(av_, wb_.y, bf_hi(ws_[p_]) + wb_.w), 0.f); \
            accv[p_].x += tx_;                                                \
            accv[p_].y += ty_;                                                \
        }                                                                     \
    }

// ---------------- CSR build ----------------

__global__ void hist_kernel(const int* __restrict__ ei, int* __restrict__ deg) {
    int e = blockIdx.x * blockDim.x + threadIdx.x;
    if (e < N_EDGES) atomicAdd(&deg[ei[N_EDGES + e]], 1);
}

#define SCAN_CHUNK 1024
#define SCAN_BLOCKS ((N_NODES + SCAN_CHUNK - 1) / SCAN_CHUNK)  // 196

// also zeroes pool+cnt (block 0) -- saves a memset range
__global__ __launch_bounds__(256) void scan_phaseA(const int* __restrict__ deg, int* __restrict__ bsums,
                                                   int* __restrict__ poolz) {
    if (blockIdx.x == 0) {
        for (int i = threadIdx.x; i < N_GRAPHS * HDIM + N_GRAPHS; i += 256) poolz[i] = 0;
    }
    __shared__ int red[256];
    int t = threadIdx.x;
    int base = blockIdx.x * SCAN_CHUNK + t * 4;
    int s = 0;
#pragma unroll
    for (int k = 0; k < 4; ++k) {
        int i = base + k;
        s += (i < N_NODES) ? deg[i] : 0;
    }
    red[t] = s;
    __syncthreads();
    for (int off = 128; off; off >>= 1) {
        if (t < off) red[t] += red[t + off];
        __syncthreads();
    }
    if (t == 0) bsums[blockIdx.x] = red[0];
}

__global__ __launch_bounds__(256) void scan_phaseB(int* __restrict__ bsums, int* __restrict__ row_ptr) {
    __shared__ int s[256];
    int t = threadIdx.x;
    int v = (t < SCAN_BLOCKS) ? bsums[t] : 0;
    s[t] = v;
    __syncthreads();
    for (int off = 1; off < 256; off <<= 1) {
        int add = (t >= off) ? s[t - off] : 0;
        __syncthreads();
        s[t] += add;
        __syncthreads();
    }
    if (t < SCAN_BLOCKS) bsums[t] = s[t] - v;  // exclusive
    if (t == SCAN_BLOCKS - 1) row_ptr[N_NODES] = s[t];
}

// also zeroes cursor -- saves a memset range
__global__ __launch_bounds__(256) void scan_phaseC(const int* __restrict__ deg,
                                                   const int* __restrict__ bsums,
                                                   int* __restrict__ row_ptr,
                                                   int* __restrict__ cursor) {
    __shared__ int ts[256];
    int t = threadIdx.x;
    int base = blockIdx.x * SCAN_CHUNK + t * 4;
    int v[4];
    int s = 0;
#pragma unroll
    for (int k = 0; k < 4; ++k) {
        int i = base + k;
        v[k] = (i < N_NODES) ? deg[i] : 0;
        s += v[k];
    }
    ts[t] = s;
    __syncthreads();
    for (int off = 1; off < 256; off <<= 1) {
        int add = (t >= off) ? ts[t - off] : 0;
        __syncthreads();
        ts[t] += add;
        __syncthreads();
    }
    int run = bsums[blockIdx.x] + ts[t] - s;
#pragma unroll
    for (int k = 0; k < 4; ++k) {
        int i = base + k;
        if (i < N_NODES) { row_ptr[i] = run; cursor[i] = 0; }
        run += v[k];
    }
}

// ---------------- Fused scatter (CSR fill) + weight packing ----------------
#define SCATTER_BLOCKS ((N_EDGES + 255) / 256)  // 1563

__global__ void scatter_pack(const int* __restrict__ ei, const float* __restrict__ ea,
                             const int* __restrict__ row_ptr, int* __restrict__ cursor,
                             int2* __restrict__ csr,
                             const float* __restrict__ s0, short* __restrict__ d0,
                             const float* __restrict__ s1, short* __restrict__ d1,
                             const float* __restrict__ s2, short* __restrict__ d2,
                             const float* __restrict__ s3, short* __restrict__ d3,
                             const float* __restrict__ s4, short* __restrict__ d4,
                             const float* __restrict__ s5, short* __restrict__ d5) {
    int b = blockIdx.x;
    if (b < SCATTER_BLOCKS) {
        int e = b * 256 + threadIdx.x;
        if (e >= N_EDGES) return;
        int d = ei[N_EDGES + e];
        int pos = atomicAdd(&cursor[d], 1);
        csr[row_ptr[d] + pos] = make_int2(ei[e], __float_as_int(ea[e]));
        return;
    }
    b -= SCATTER_BLOCKS;
    const float* W;
    short* D;
    int din, KP, b0;
    if (b < 16)       { W = s0; D = d0; din = 5;   KP = 32;  b0 = 0; }
    else if (b < 80)  { W = s1; D = d1; din = 128; KP = 128; b0 = 16; }
    else if (b < 144) { W = s2; D = d2; din = 128; KP = 128; b0 = 80; }
    else if (b < 208) { W = s3; D = d3; din = 128; KP = 128; b0 = 144; }
    else if (b < 272) { W = s4; D = d4; din = 128; KP = 128; b0 = 208; }
    else              { W = s5; D = d5; din = 128; KP = 128; b0 = 272; }
    int idx = (b - b0) * 256 + threadIdx.x;
    if (idx >= KP * 128) return;
    int j = idx & 7;
    int lane = (idx >> 3) & 63;
    int rest = idx >> 9;
    int KS = KP >> 5;
    int kstep = rest % KS;
    int tile = rest / KS;
    int k = kstep * 32 + ((lane >> 4) * 8) + j;
    int n = tile * 16 + (lane & 15);
    float v = (k < din) ? W[k * 128 + n] : 0.f;
    D[idx] = (short)to_bf(v);
}

// ---------------- Fused layer: gather + MFMA MLP + reg-LN + ReLU (+pool) ----------------
// 256 threads = 4 waves; 64 nodes/block. (256,4): VGPR cap 128 -> gather pipeline
// (2-buffer, ~85 live) fits without spill.
template <int KP1, bool POOL>
__global__ __launch_bounds__(256, 4) void layer_fused(
    const void* __restrict__ xin_v, const int* __restrict__ row_ptr,
    const int2* __restrict__ csr,
    const float* __restrict__ ew, const float* __restrict__ eb,
    const short* __restrict__ w1h, const float* __restrict__ b1,
    const short* __restrict__ w2h, const float* __restrict__ b2,
    const float* __restrict__ g, const float* __restrict__ bt,
    unsigned short* __restrict__ xout,
    const int* __restrict__ batch, float* __restrict__ pool, int* __restrict__ cnt) {
    __shared__ __align__(16) unsigned short A16[NPBLK * LDA];
    __shared__ int bidx[NPBLK];
    union Scratch {
        float eweb4[4 * 17 * 4];                       // padded {ew,ew,eb,eb} float4 table (din=128 path)
        float part[KP1 == 128 ? 1 : NPBLK][4][INDIM];  // layer-0 gather partials
    };
    __shared__ __align__(16) Scratch u;

    int tid = threadIdx.x;
    int node0 = blockIdx.x * NPBLK;

    if constexpr (KP1 == 128) {
        const unsigned short* xin = (const unsigned short*)xin_v;
        // stage padded edge-encoder table: group qt at float4 stride 17 (bank-conflict-free broadcast reads)
        if (tid < 64) {
            int qq = tid >> 4, ii = tid & 15, c = qq * 32 + ii * 2;
            ((float4*)u.eweb4)[qq * 17 + ii] = make_float4(ew[c], ew[c + 1], eb[c], eb[c + 1]);
        }
        if (POOL && tid >= 64 && tid < 128) bidx[tid - 64] = batch[node0 + tid - 64];

        // thread = (row, 32-channel quarter); f32x2 accumulators in registers
        int row = tid >> 2, qt = tid & 3, c0 = qt * 32;
        int node = node0 + row;

        // issue own-row load + 2-edge pipeline preamble before the barrier (in flight across it)
        const uint4* xn = (const uint4*)(xin + (size_t)node * 128 + c0);
        uint4 o0 = xn[0], o1 = xn[1], o2 = xn[2], o3 = xn[3];
        int beg = row_ptr[node], end = row_ptr[node + 1];

        uint4 va0, va1, va2, va3, vb0, vb1, vb2, vb3;
        float aA = 0.f, aB = 0.f;
        if (beg < end) {
            int2 r = csr[beg];
            aA = __int_as_float(r.y);
            GLOAD(va0, va1, va2, va3, r.x);
        }
        if (beg + 1 < end) {
            int2 r = csr[beg + 1];
            aB = __int_as_float(r.y);
            GLOAD(vb0, vb1, vb2, vb3, r.x);
        }
        __syncthreads();  // eweb4 ready
        const float4* ep = ((const float4*)u.eweb4) + qt * 17;

        f32x2 accv[16];
        {
            unsigned ws_[16] = {o0.x, o0.y, o0.z, o0.w, o1.x, o1.y, o1.z, o1.w,
                                o2.x, o2.y, o2.z, o2.w, o3.x, o3.y, o3.z, o3.w};
#pragma unroll
            for (int p = 0; p < 16; ++p) {
                accv[p].x = bf_lo(ws_[p]);
                accv[p].y = bf_hi(ws_[p]);
            }
        }

        // software-pipelined gather: consume A (edge e) while B (e+1) in flight; refill A with e+2; etc.
        int e = beg;
        while (e + 3 < end) {
            GPROC(va0, va1, va2, va3, aA);
            {
                int2 r = csr[e + 2];
                aA = __int_as_float(r.y);
                GLOAD(va0, va1, va2, va3, r.x);
            }
            GPROC(vb0, vb1, vb2, vb3, aB);
            {
                int2 r = csr[e + 3];
                aB = __int_as_float(r.y);
                GLOAD(vb0, vb1, vb2, vb3, r.x);
            }
            e += 2;
        }
        // drain: at most 3 edges remain (e, e+1, e+2); A/B hold e, e+1 if in range
        if (e < end) GPROC(va0, va1, va2, va3, aA);
        if (e + 1 < end) GPROC(vb0, vb1, vb2, vb3, aB);
        if (e + 2 < end) {
            int2 r = csr[e + 2];
            GLOAD(va0, va1, va2, va3, r.x);
            GPROC(va0, va1, va2, va3, __int_as_float(r.y));
        }

        // packed cvt + uint2 stores (2-way bank aliasing only = free)
        uint2* Ar2 = (uint2*)&A16[row * LDA + c0];
#pragma unroll
        for (int k = 0; k < 8; ++k) {
            Ar2[k] = make_uint2(cvt2_bf(accv[2 * k].x, accv[2 * k].y),
                                cvt2_bf(accv[2 * k + 1].x, accv[2 * k + 1].y));
        }
        // no barrier: rows [16wv,16wv+16) are written and read by the same wave
    } else {
        // layer 0 (din=5): 4 threads/row split the edge list; register partials
        const float* xinf = (const float*)xin_v;
        int row = tid >> 2, qt = tid & 3;
        int node = node0 + row;
        {
            float w[INDIM], b[INDIM], acc[INDIM];
#pragma unroll
            for (int j = 0; j < INDIM; ++j) {
                w[j] = ew[j];
                b[j] = eb[j];
                acc[j] = 0.f;
            }
            int beg = row_ptr[node], end = row_ptr[node + 1];
            int2 r;
            if (beg + qt < end) r = csr[beg + qt];
            for (int e = beg + qt; e < end; e += 4) {
                int2 rn = (e + 4 < end) ? csr[e + 4] : r;
                float a = __int_as_float(r.y);
#pragma unroll
                for (int j = 0; j < INDIM; ++j)
                    acc[j] += fmaxf(fmaf(a, w[j], xinf[r.x * INDIM + j] + b[j]), 0.f);
                r = rn;
            }
#pragma unroll
            for (int j = 0; j < INDIM; ++j) u.part[row][qt][j] = acc[j];
        }
        __syncthreads();
        if (tid < NPBLK) {
#pragma unroll
            for (int j = 0; j < INDIM; ++j) {
                float v = xinf[(node0 + tid) * INDIM + j] + u.part[tid][0][j] + u.part[tid][1][j] +
                          u.part[tid][2][j] + u.part[tid][3][j];
                A16[tid * LDA + j] = cvt1_bf(v);
            }
#pragma unroll
            for (int j = INDIM; j < 32; ++j) A16[tid * LDA + j] = 0;
        }
        __syncthreads();  // rows written by tid<64 -> cross-wave
    }

    // ---- MFMA MLP (wave-local rows) ----
    int wv = tid >> 6, lane = tid & 63;
    int mrow = lane & 15, q = lane >> 4;
    int arow = wv * 16 + mrow;

    const short8* w1p = (const short8*)w1h;
    const short8* w2p = (const short8*)w2h;

    f32x4 acc2[8];
#pragma unroll
    for (int t = 0; t < 8; ++t) acc2[t] = (f32x4){0.f, 0.f, 0.f, 0.f};
    constexpr int KS1 = KP1 / 32;
#pragma unroll
    for (int ks = 0; ks < KS1; ++ks) {
        short8 bh[8];
#pragma unroll
        for (int t = 0; t < 8; ++t) bh[t] = w1p[((size_t)t * KS1 + ks) * 64 + lane];
        short8 ah = *(const short8*)&A16[arow * LDA + ks * 32 + q * 8];
#pragma unroll
        for (int t = 0; t < 8; ++t)
            acc2[t] = __builtin_amdgcn_mfma_f32_16x16x32_bf16(ah, bh[t], acc2[t], 0, 0, 0);
    }
    // t1 = relu(acc + b1) -> bf16 A (wave-local rows)
    {
        float b1v[8];
#pragma unroll
        for (int t = 0; t < 8; ++t) b1v[t] = b1[t * 16 + mrow];
#pragma unroll
        for (int t = 0; t < 8; ++t)
#pragma unroll
            for (int r = 0; r < 4; ++r) {
                int rrow = wv * 16 + q * 4 + r;
                int col = t * 16 + mrow;
                A16[rrow * LDA + col] = cvt1_bf(fmaxf(acc2[t][r] + b1v[t], 0.f));
            }
    }

    // GEMM2 (K = 128); A reads wave-local
#pragma unroll
    for (int t = 0; t < 8; ++t) acc2[t] = (f32x4){0.f, 0.f, 0.f, 0.f};
#pragma unroll
    for (int ks = 0; ks < 4; ++ks) {
        short8 bh[8];
#pragma unroll
        for (int t = 0; t < 8; ++t) bh[t] = w2p[((size_t)t * 4 + ks) * 64 + lane];
        short8 ah = *(const short8*)&A16[arow * LDA + ks * 32 + q * 8];
#pragma unroll
        for (int t = 0; t < 8; ++t)
            acc2[t] = __builtin_amdgcn_mfma_f32_16x16x32_bf16(ah, bh[t], acc2[t], 0, 0, 0);
    }

    // ---- LayerNorm in registers (rows live in 16-lane groups) ----
    float s4[4] = {0.f, 0.f, 0.f, 0.f}, q4[4] = {0.f, 0.f, 0.f, 0.f};
    {
        float b2v[8];
#pragma unroll
        for (int t = 0; t < 8; ++t) b2v[t] = b2[t * 16 + mrow];
#pragma unroll
        for (int t = 0; t < 8; ++t)
#pragma unroll
            for (int r = 0; r < 4; ++r) {
                float v = acc2[t][r] + b2v[t];
                acc2[t][r] = v;
                s4[r] += v;
                q4[r] += v * v;
            }
    }
#pragma unroll
    for (int m = 1; m <= 8; m <<= 1) {
#pragma unroll
        for (int r = 0; r < 4; ++r) {
            s4[r] += __shfl_xor(s4[r], m, 64);
            q4[r] += __shfl_xor(q4[r], m, 64);
        }
    }
    float mu[4], inv[4];
#pragma unroll
    for (int r = 0; r < 4; ++r) {
        mu[r] = s4[r] * (1.f / HDIM);
        float var = q4[r] * (1.f / HDIM) - mu[r] * mu[r];
        inv[r] = rsqrtf(var + LN_EPS);
    }
    float gv[8], btv[8];
#pragma unroll
    for (int t = 0; t < 8; ++t) {
        gv[t] = g[t * 16 + mrow];
        btv[t] = bt[t * 16 + mrow];
    }

    // LN result -> LDS (wave-local row writes; no pre-barrier needed)
#pragma unroll
    for (int t = 0; t < 8; ++t)
#pragma unroll
        for (int r = 0; r < 4; ++r) {
            int rrow = wv * 16 + q * 4 + r;
            int col = t * 16 + mrow;
            float o = fmaxf((acc2[t][r] - mu[r]) * inv[r] * gv[t] + btv[t], 0.f);
            A16[rrow * LDA + col] = cvt1_bf(o);
        }
    __syncthreads();  // epilogue reads all rows (cross-wave)

    if (!POOL) {
        // coalesced copy-out: wave inst covers 256 contiguous bytes (4 full lines)
        unsigned* xo = (unsigned*)xout;
#pragma unroll
        for (int i = 0; i < 16; ++i) {
            int idx = tid + 256 * i;       // 4096 = 64 rows x 64 words
            int row = idx >> 6, w = idx & 63;
            xo[(size_t)(node0 + row) * 64 + w] = ((const unsigned*)&A16[row * LDA])[w];
        }
    } else {
        if (tid < 128) {
            int col = tid;
            float accp = 0.f;
            int cur = bidx[0];
            for (int r = 0; r < NPBLK; ++r) {
                int gi = bidx[r];
                if (gi != cur) {
                    unsafeAtomicAdd(&pool[cur * HDIM + col], accp);
                    accp = 0.f;
                    cur = gi;
                }
                accp += bf2f(A16[r * LDA + col]);
            }
            unsafeAtomicAdd(&pool[cur * HDIM + col], accp);
        } else if (tid == 255) {
            int cur = bidx[0], c = 0;
            for (int r = 0; r < NPBLK; ++r) {
                if (bidx[r] != cur) {
                    atomicAdd(&cnt[cur], c);
                    c = 0;
                    cur = bidx[r];
                }
                ++c;
            }
            atomicAdd(&cnt[cur], c);
        }
    }
}

__global__ void pool_final(const float* __restrict__ pool, const int* __restrict__ cnt,
                           float* __restrict__ out) {
    int g = blockIdx.x, j = threadIdx.x;
    float add = pool[g * HDIM + j];
    float c = (float)max(cnt[g], 1);
    out[g * (2 * HDIM) + j] = add / c;
    out[g * (2 * HDIM) + HDIM + j] = add;
}

extern "C" void kernel_launch(void* const* d_in, const int* in_sizes, int n_in,
                              void* d_out, int out_size, void* d_ws, size_t ws_size,
                              hipStream_t stream) {
    const float* x_in = (const float*)d_in[0];
    const int* ei = (const int*)d_in[1];
    const float* ea = (const float*)d_in[2];
    const int* batch = (const int*)d_in[3];
    const float* P[24];
    for (int i = 0; i < 24; ++i) P[i] = (const float*)d_in[4 + i];
    // per layer l (base 8l): 0=ew 1=eb 2=w1 3=b1 4=w2 5=b2 6=g 7=bt

    unsigned short* x_a = (unsigned short*)d_ws;                 // N*128 bf16
    unsigned short* x_b = x_a + (size_t)N_NODES * HDIM;          // N*128 bf16
    float* pool = (float*)(x_b + (size_t)N_NODES * HDIM);        // G*128 (zeroed in scanA)
    int* cnt = (int*)(pool + N_GRAPHS * HDIM);                   // G    (zeroed in scanA)
    int* deg = cnt + N_GRAPHS;                                   // N    (memset)
    int* cursor = deg + N_NODES;                                 // N    (zeroed in scanC)
    int* row_ptr = cursor + N_NODES;                             // N+1
    int* bsums = row_ptr + N_NODES + 1;                          // pad 256 (keeps int2 8B-aligned)
    int2* csr = (int2*)(bsums + 256);                            // E (packed {src, val})
    short* wp = (short*)(((uintptr_t)(csr + N_EDGES) + 15) & ~(uintptr_t)15);
    float* out = (float*)d_out;

    short *w1h[3], *w2h[3];
    for (int l = 0; l < 3; ++l) {
        w1h[l] = wp + (size_t)l * 32768;
        w2h[l] = w1h[l] + 16384;
    }

    // ---- memset: deg only (pool/cnt zeroed in scanA, cursor in scanC) ----
    hipMemsetAsync(deg, 0, N_NODES * sizeof(int), stream);

    // ---- CSR build ----
    hist_kernel<<<(N_EDGES + 255) / 256, 256, 0, stream>>>(ei, deg);
    scan_phaseA<<<SCAN_BLOCKS, 256, 0, stream>>>(deg, bsums, (int*)pool);
    scan_phaseB<<<1, 256, 0, stream>>>(bsums, row_ptr);
    scan_phaseC<<<SCAN_BLOCKS, 256, 0, stream>>>(deg, bsums, row_ptr, cursor);

    // ---- fused scatter + weight packing (1563 + 336 blocks) ----
    scatter_pack<<<SCATTER_BLOCKS + 336, 256, 0, stream>>>(
        ei, ea, row_ptr, cursor, csr,
        P[2], w1h[0], P[4], w2h[0],
        P[10], w1h[1], P[12], w2h[1],
        P[18], w1h[2], P[20], w2h[2]);

    // ---- fused layers ----
    layer_fused<32, false><<<N_NODES / NPBLK, 256, 0, stream>>>(
        x_in, row_ptr, csr, P[0], P[1],
        w1h[0], P[3], w2h[0], P[5], P[6], P[7], x_a, nullptr, nullptr, nullptr);
    layer_fused<128, false><<<N_NODES / NPBLK, 256, 0, stream>>>(
        x_a, row_ptr, csr, P[8], P[9],
        w1h[1], P[11], w2h[1], P[13], P[14], P[15], x_b, nullptr, nullptr, nullptr);
    layer_fused<128, true><<<N_NODES / NPBLK, 256, 0, stream>>>(
        x_b, row_ptr, csr, P[16], P[17],
        w1h[2], P[19], w2h[2], P[21], P[22], P[23], nullptr, batch, pool, cnt);

    pool_final<<<N_GRAPHS, HDIM, 0, stream>>>(pool, cnt, out);
}